// Round 1
// baseline (221.396 us; speedup 1.0000x reference)
//
#include <hip/hip_runtime.h>
#include <hip/hip_bf16.h>

// Token constants from the reference
constexpr int PAD_T = 10, BOS_T = 11, EOS_T = 12, ROW_T = 13, SEP_T = 14;
constexpr int Bc = 16, Tc = 4096, Dc = 512;
constexpr int MAXH = 30, MAXW = 30;

// ---------------------------------------------------------------------------
// Kernel A: parallel scan of the 2D-position automaton.
// One wave (64 lanes) per sequence. Each lane summarizes a 64-token chunk as a
// composable transition function, a Hillis-Steele shuffle scan composes them,
// then each lane replays its chunk emitting packed (r<<5)|c per token.
//
// Summary of a chunk (state = row, col, grid):
//   row: grid-independent. row_keep = no BOS/SEP in chunk; r = row delta/abs.
//   col: col_keep = no BOS/SEP/ROW; c0/c1 = col result for grid_in = 0/1.
//   grid: g0/g1 = grid_out for grid_in = 0/1.
// ---------------------------------------------------------------------------
__global__ __launch_bounds__(64) void scan_kernel(const int* __restrict__ ids,
                                                  int* __restrict__ packed) {
    const int b = blockIdx.x;
    const int lane = threadIdx.x;           // 0..63
    const int CH = Tc / 64;                 // 64 tokens per lane
    const int* seq = ids + b * Tc;
    const int base = lane * CH;

    // --- local chunk summary (dual grid-in simulation) ---
    int r = 0, c0 = 0, c1 = 0;
    int g0 = 0, g1 = 1;
    int row_keep = 1, col_keep = 1;
    for (int j = 0; j < CH; ++j) {
        int tok = seq[base + j];
        if (tok == BOS_T)      { g0 = 1; g1 = 1; r = 0; c0 = 0; c1 = 0; row_keep = 0; col_keep = 0; }
        else if (tok == SEP_T) { r = 0; c0 = 0; c1 = 0; row_keep = 0; col_keep = 0; }
        else if (tok == ROW_T) { r += 1; c0 = 0; c1 = 0; col_keep = 0; }
        else if (tok == EOS_T || tok == PAD_T) { g0 = 0; g1 = 0; }
        else { c0 += g0; c1 += g1; }        // digit 0..9
    }

    // --- inclusive scan: compose (other-first, then me) ---
    for (int d = 1; d < 64; d <<= 1) {
        int o_r  = __shfl_up(r, d);
        int o_c0 = __shfl_up(c0, d);
        int o_c1 = __shfl_up(c1, d);
        int o_g0 = __shfl_up(g0, d);
        int o_g1 = __shfl_up(g1, d);
        int o_rk = __shfl_up(row_keep, d);
        int o_ck = __shfl_up(col_keep, d);
        if (lane >= d) {
            int gmid0 = o_g0, gmid1 = o_g1;      // grid after "other" for grid_in=0/1
            int h_g0 = gmid0 ? g1 : g0;
            int h_g1 = gmid1 ? g1 : g0;
            int h_r  = row_keep ? (o_r + r) : r;
            int h_rk = row_keep & o_rk;
            int me_c_g0 = gmid0 ? c1 : c0;
            int me_c_g1 = gmid1 ? c1 : c0;
            int h_c0 = col_keep ? (o_c0 + me_c_g0) : me_c_g0;
            int h_c1 = col_keep ? (o_c1 + me_c_g1) : me_c_g1;
            int h_ck = col_keep & o_ck;
            g0 = h_g0; g1 = h_g1; r = h_r; row_keep = h_rk;
            c0 = h_c0; c1 = h_c1; col_keep = h_ck;
        }
    }

    // --- exclusive state at chunk start: apply lanes [0..lane-1] to (0,0,grid=0) ---
    int s_r = __shfl_up(r, 1);
    int s_c = __shfl_up(c0, 1);
    int s_g = __shfl_up(g0, 1);
    if (lane == 0) { s_r = 0; s_c = 0; s_g = 0; }

    // --- replay, emitting pre-update (clipped) positions ---
    int row = s_r, col = s_c, grid = s_g;
    int* outp = packed + b * Tc + base;
    for (int j = 0; j < CH; ++j) {
        int tok = seq[base + j];
        int gc = grid & (tok <= 9);
        int er = gc ? min(row, MAXH - 1) : 0;
        int ec = gc ? min(col, MAXW - 1) : 0;
        outp[j] = (er << 5) | ec;
        if (tok == BOS_T)      { grid = 1; row = 0; col = 0; }
        else if (tok == SEP_T) { row = 0; col = 0; }
        else if (tok == ROW_T) { row += 1; col = 0; }
        else if (tok == EOS_T || tok == PAD_T) { grid = 0; }
        else { col += gc; }
    }
}

// ---------------------------------------------------------------------------
// Kernel B: collapse the einsum. Frow[r][e] = dot(row_table[r,:], W[e, 0:256]),
// Fcol[c][e] = dot(col_table[c,:], W[e, 256:512]).  60 blocks, ~8 MFLOP total.
// ---------------------------------------------------------------------------
__global__ __launch_bounds__(256) void precompute_kernel(
        const float* __restrict__ row_table, const float* __restrict__ col_table,
        const float* __restrict__ w,           // (512 e, 512 d) row-major
        float* __restrict__ frow, float* __restrict__ fcol) {
    const int which = blockIdx.x / 30;         // 0 -> Frow, 1 -> Fcol
    const int rr = blockIdx.x % 30;
    const float* src = which ? (col_table + rr * 256) : (row_table + rr * 256);
    float* dst = which ? (fcol + rr * Dc) : (frow + rr * Dc);
    const int doff = which ? 256 : 0;

    __shared__ __align__(16) float s[256];
    s[threadIdx.x] = src[threadIdx.x];
    __syncthreads();

    const float4* sv = (const float4*)s;
    for (int e = threadIdx.x; e < Dc; e += 256) {
        const float4* wrow = (const float4*)(w + (size_t)e * Dc + doff);
        float acc = 0.f;
#pragma unroll 8
        for (int k = 0; k < 64; ++k) {
            float4 a = sv[k];
            float4 wb = wrow[k];
            acc += a.x * wb.x + a.y * wb.y + a.z * wb.z + a.w * wb.w;
        }
        dst[e] = acc;
    }
}

// ---------------------------------------------------------------------------
// Kernel C: fused embed-add + LayerNorm. One wave per token (8 floats/lane),
// 4 tokens per 256-thread block. Memory-bound: 134 MB out + ~8 MB pos read.
// ---------------------------------------------------------------------------
__global__ __launch_bounds__(256) void fuse_ln_kernel(
        const int* __restrict__ ids, const int* __restrict__ packed,
        const float* __restrict__ token_table, const float* __restrict__ pos_table,
        const float* __restrict__ frow, const float* __restrict__ fcol,
        const float* __restrict__ gamma, const float* __restrict__ beta,
        float* __restrict__ out) {
    const int wave = threadIdx.x >> 6;
    const int lane = threadIdx.x & 63;
    const int idx = blockIdx.x * 4 + wave;   // token index in [0, B*T)
    const int t = idx & (Tc - 1);
    const int tok = ids[idx];                // broadcast load
    const int pk = packed[idx];
    const int rI = pk >> 5, cI = pk & 31;
    const float mask = (tok <= 9) ? 1.0f : 0.0f;
    const int d0 = lane * 8;

    float xt[8], xp[8], xf[8], xc[8];
    *(float4*)(xt + 0) = *(const float4*)(token_table + (size_t)tok * Dc + d0);
    *(float4*)(xt + 4) = *(const float4*)(token_table + (size_t)tok * Dc + d0 + 4);
    *(float4*)(xp + 0) = *(const float4*)(pos_table + (size_t)t * Dc + d0);
    *(float4*)(xp + 4) = *(const float4*)(pos_table + (size_t)t * Dc + d0 + 4);
    *(float4*)(xf + 0) = *(const float4*)(frow + (size_t)rI * Dc + d0);
    *(float4*)(xf + 4) = *(const float4*)(frow + (size_t)rI * Dc + d0 + 4);
    *(float4*)(xc + 0) = *(const float4*)(fcol + (size_t)cI * Dc + d0);
    *(float4*)(xc + 4) = *(const float4*)(fcol + (size_t)cI * Dc + d0 + 4);

    float x[8];
    float s = 0.f, sq = 0.f;
#pragma unroll
    for (int j = 0; j < 8; ++j) {
        float v = xt[j] + xp[j] + mask * (xf[j] + xc[j]);
        x[j] = v;
        s += v;
        sq = fmaf(v, v, sq);
    }
    // wave-64 butterfly reduction of (sum, sumsq)
#pragma unroll
    for (int m = 1; m < 64; m <<= 1) {
        s  += __shfl_xor(s, m);
        sq += __shfl_xor(sq, m);
    }
    const float mu  = s * (1.0f / Dc);
    const float var = fmaf(-mu, mu, sq * (1.0f / Dc));
    const float inv = rsqrtf(var + 1e-5f);

    float g[8], bb[8], y[8];
    *(float4*)(g + 0)  = *(const float4*)(gamma + d0);
    *(float4*)(g + 4)  = *(const float4*)(gamma + d0 + 4);
    *(float4*)(bb + 0) = *(const float4*)(beta + d0);
    *(float4*)(bb + 4) = *(const float4*)(beta + d0 + 4);
#pragma unroll
    for (int j = 0; j < 8; ++j) {
        y[j] = fmaf((x[j] - mu) * inv, g[j], bb[j]);
    }
    float* op = out + (size_t)idx * Dc + d0;
    *(float4*)(op + 0) = *(const float4*)(y + 0);
    *(float4*)(op + 4) = *(const float4*)(y + 4);
}

extern "C" void kernel_launch(void* const* d_in, const int* in_sizes, int n_in,
                              void* d_out, int out_size, void* d_ws, size_t ws_size,
                              hipStream_t stream) {
    const int*   ids         = (const int*)d_in[0];
    const float* token_table = (const float*)d_in[1];
    const float* pos_table   = (const float*)d_in[2];
    const float* row_table   = (const float*)d_in[3];
    const float* col_table   = (const float*)d_in[4];
    const float* w_spatial   = (const float*)d_in[5];
    const float* ln_gamma    = (const float*)d_in[6];
    const float* ln_beta     = (const float*)d_in[7];
    float* out = (float*)d_out;

    char* ws = (char*)d_ws;
    int*   packed = (int*)ws;                         // 16*4096*4   = 256 KiB
    float* frow   = (float*)(ws + (256 << 10));       // 30*512*4    = 60 KiB
    float* fcol   = (float*)(ws + (256 << 10) + (64 << 10));

    hipLaunchKernelGGL(scan_kernel, dim3(Bc), dim3(64), 0, stream, ids, packed);
    hipLaunchKernelGGL(precompute_kernel, dim3(60), dim3(256), 0, stream,
                       row_table, col_table, w_spatial, frow, fcol);
    hipLaunchKernelGGL(fuse_ln_kernel, dim3(Bc * Tc / 4), dim3(256), 0, stream,
                       ids, packed, token_table, pos_table, frow, fcol,
                       ln_gamma, ln_beta, out);
}

// Round 2
// 202.713 us; speedup vs baseline: 1.0922x; 1.0922x over previous
//
#include <hip/hip_runtime.h>
#include <hip/hip_bf16.h>

constexpr int PAD_T = 10, BOS_T = 11, EOS_T = 12, ROW_T = 13, SEP_T = 14;
constexpr int Bc = 16, Tc = 4096, Dc = 512;
constexpr int MAXH = 30, MAXW = 30;

typedef float fvec4 __attribute__((ext_vector_type(4)));

// Composable transition summary of a token chunk.
// g0/g1: grid_out for grid_in=0/1. r: row delta (abs if rk=0), rk: no row reset.
// c0/c1: col delta given grid_in=0/1 (abs if ck=0), ck: no col reset.
struct Summ { int r, c0, c1, g0, g1, rk, ck; };

__device__ inline void tok_update(int tok, Summ& s) {
    if (tok == BOS_T)      { s.g0 = 1; s.g1 = 1; s.r = 0; s.c0 = 0; s.c1 = 0; s.rk = 0; s.ck = 0; }
    else if (tok == SEP_T) { s.r = 0; s.c0 = 0; s.c1 = 0; s.rk = 0; s.ck = 0; }
    else if (tok == ROW_T) { s.r += 1; s.c0 = 0; s.c1 = 0; s.ck = 0; }
    else if (tok == EOS_T || tok == PAD_T) { s.g0 = 0; s.g1 = 0; }
    else { s.c0 += s.g0; s.c1 += s.g1; }   // digit 0..9
}

// out = a (earlier) then b (later)
__device__ inline Summ compose(const Summ& a, const Summ& b) {
    Summ o;
    o.g0 = a.g0 ? b.g1 : b.g0;
    o.g1 = a.g1 ? b.g1 : b.g0;
    o.r  = b.rk ? a.r + b.r : b.r;
    o.rk = a.rk & b.rk;
    int cm0 = a.g0 ? b.c1 : b.c0;
    int cm1 = a.g1 ? b.c1 : b.c0;
    o.c0 = b.ck ? a.c0 + cm0 : cm0;
    o.c1 = b.ck ? a.c1 + cm1 : cm1;
    o.ck = a.ck & b.ck;
    return o;
}

// Apply summary s to concrete state (r,c,g)
__device__ inline void apply_state(const Summ& s, int& r, int& c, int& g) {
    int cm = g ? s.c1 : s.c0;
    r = s.rk ? r + s.r : s.r;
    c = s.ck ? c + cm : cm;
    g = g ? s.g1 : s.g0;
}

// ---------------------------------------------------------------------------
// Dispatch 1 (merged): blocks 0..15 = parallel automaton scan (one 1024-thread
// block per sequence, 4 tokens/lane); blocks 16..75 = einsum collapse
// Frow = row_table @ W[:, :256]^T, Fcol = col_table @ W[:, 256:]^T.
// ---------------------------------------------------------------------------
__global__ __launch_bounds__(1024) void scan_pre_kernel(
        const int* __restrict__ ids, int* __restrict__ packed,
        const float* __restrict__ row_table, const float* __restrict__ col_table,
        const float* __restrict__ w,
        float* __restrict__ frow, float* __restrict__ fcol) {
    if (blockIdx.x < 16) {
        const int b = blockIdx.x;
        const int tid = threadIdx.x;          // 0..1023
        const int lane = tid & 63, wid = tid >> 6;

        // coalesced int4 load of this lane's 4 tokens
        const int4 tk4 = *(const int4*)(ids + b * Tc + tid * 4);
        int tks[4] = {tk4.x, tk4.y, tk4.z, tk4.w};

        // chunk summary
        Summ s{0, 0, 0, 0, 1, 1, 1};
#pragma unroll
        for (int j = 0; j < 4; ++j) tok_update(tks[j], s);

        // intra-wave inclusive scan
        Summ inc = s;
#pragma unroll
        for (int d = 1; d < 64; d <<= 1) {
            Summ o;
            o.r  = __shfl_up(inc.r, d);
            o.c0 = __shfl_up(inc.c0, d);
            o.c1 = __shfl_up(inc.c1, d);
            o.g0 = __shfl_up(inc.g0, d);
            o.g1 = __shfl_up(inc.g1, d);
            o.rk = __shfl_up(inc.rk, d);
            o.ck = __shfl_up(inc.ck, d);
            if (lane >= d) inc = compose(o, inc);
        }

        // wave totals -> LDS
        __shared__ int lsum[16][7];
        if (lane == 63) {
            lsum[wid][0] = inc.r;  lsum[wid][1] = inc.c0; lsum[wid][2] = inc.c1;
            lsum[wid][3] = inc.g0; lsum[wid][4] = inc.g1;
            lsum[wid][5] = inc.rk; lsum[wid][6] = inc.ck;
        }
        __syncthreads();

        // wave-start concrete state: apply preceding wave summaries to (0,0,0)
        int wr = 0, wc = 0, wg = 0;
        for (int w2 = 0; w2 < wid; ++w2) {
            Summ t;
            t.r  = lsum[w2][0]; t.c0 = lsum[w2][1]; t.c1 = lsum[w2][2];
            t.g0 = lsum[w2][3]; t.g1 = lsum[w2][4];
            t.rk = lsum[w2][5]; t.ck = lsum[w2][6];
            apply_state(t, wr, wc, wg);
        }

        // lane-start state = wave state + exclusive intra-wave summary
        Summ ex;
        ex.r  = __shfl_up(inc.r, 1);  ex.c0 = __shfl_up(inc.c0, 1);
        ex.c1 = __shfl_up(inc.c1, 1); ex.g0 = __shfl_up(inc.g0, 1);
        ex.g1 = __shfl_up(inc.g1, 1); ex.rk = __shfl_up(inc.rk, 1);
        ex.ck = __shfl_up(inc.ck, 1);
        if (lane == 0) { ex = Summ{0, 0, 0, 0, 1, 1, 1}; }  // identity
        int row = wr, col = wc, grid = wg;
        apply_state(ex, row, col, grid);

        // replay 4 tokens, pack (r<<5)|c, int4 store
        int o4[4];
#pragma unroll
        for (int j = 0; j < 4; ++j) {
            int tok = tks[j];
            int gc = grid & (tok <= 9);
            int er = gc ? min(row, MAXH - 1) : 0;
            int ec = gc ? min(col, MAXW - 1) : 0;
            o4[j] = (er << 5) | ec;
            if (tok == BOS_T)      { grid = 1; row = 0; col = 0; }
            else if (tok == SEP_T) { row = 0; col = 0; }
            else if (tok == ROW_T) { row += 1; col = 0; }
            else if (tok == EOS_T || tok == PAD_T) { grid = 0; }
            else { col += gc; }
        }
        *(int4*)(packed + b * Tc + tid * 4) = make_int4(o4[0], o4[1], o4[2], o4[3]);
    } else {
        // ---- einsum collapse ----
        const int blk = blockIdx.x - 16;
        const int which = blk / 30;            // 0 -> Frow, 1 -> Fcol
        const int rr = blk % 30;
        const float* src = which ? (col_table + rr * 256) : (row_table + rr * 256);
        float* dst = which ? (fcol + rr * Dc) : (frow + rr * Dc);
        const int doff = which ? 256 : 0;

        __shared__ __align__(16) float sv[256];
        if (threadIdx.x < 256) sv[threadIdx.x] = src[threadIdx.x];
        __syncthreads();

        if (threadIdx.x < 512) {
            const int e = threadIdx.x;
            const float4* a4 = (const float4*)sv;
            const float4* w4 = (const float4*)(w + (size_t)e * Dc + doff);
            float acc = 0.f;
#pragma unroll 8
            for (int k = 0; k < 64; ++k) {
                float4 a = a4[k];
                float4 wb = w4[k];
                acc += a.x * wb.x + a.y * wb.y + a.z * wb.z + a.w * wb.w;
            }
            dst[e] = acc;
        }
    }
}

// ---------------------------------------------------------------------------
// Dispatch 2: fused embed-add + LayerNorm. One wave per token, t-major token
// ordering so pos_table rows are reused by 16 adjacent waves (L2 hits).
// Streaming nontemporal stores for the 134 MB output.
// ---------------------------------------------------------------------------
__global__ __launch_bounds__(256) void fuse_ln_kernel(
        const int* __restrict__ ids, const int* __restrict__ packed,
        const float* __restrict__ token_table, const float* __restrict__ pos_table,
        const float* __restrict__ frow, const float* __restrict__ fcol,
        const float* __restrict__ gamma, const float* __restrict__ beta,
        float* __restrict__ out) {
    const int wave = threadIdx.x >> 6;
    const int lane = threadIdx.x & 63;
    const int g = blockIdx.x * 4 + wave;     // (t, b) pair, b fastest
    const int b = g & (Bc - 1);
    const int t = g >> 4;
    const int idx = b * Tc + t;
    const int tok = ids[idx];                // wave-uniform
    const int pk = packed[idx];
    const int rI = pk >> 5, cI = pk & 31;
    const int d0 = lane * 8;

    float xt[8], xp[8];
    *(float4*)(xt + 0) = *(const float4*)(token_table + (size_t)tok * Dc + d0);
    *(float4*)(xt + 4) = *(const float4*)(token_table + (size_t)tok * Dc + d0 + 4);
    *(float4*)(xp + 0) = *(const float4*)(pos_table + (size_t)t * Dc + d0);
    *(float4*)(xp + 4) = *(const float4*)(pos_table + (size_t)t * Dc + d0 + 4);

    float x[8];
#pragma unroll
    for (int j = 0; j < 8; ++j) x[j] = xt[j] + xp[j];

    if (tok <= 9) {                          // wave-uniform branch: grid color
        float xf[8], xc[8];
        *(float4*)(xf + 0) = *(const float4*)(frow + (size_t)rI * Dc + d0);
        *(float4*)(xf + 4) = *(const float4*)(frow + (size_t)rI * Dc + d0 + 4);
        *(float4*)(xc + 0) = *(const float4*)(fcol + (size_t)cI * Dc + d0);
        *(float4*)(xc + 4) = *(const float4*)(fcol + (size_t)cI * Dc + d0 + 4);
#pragma unroll
        for (int j = 0; j < 8; ++j) x[j] += xf[j] + xc[j];
    }

    float s = 0.f, sq = 0.f;
#pragma unroll
    for (int j = 0; j < 8; ++j) {
        s += x[j];
        sq = fmaf(x[j], x[j], sq);
    }
#pragma unroll
    for (int m = 1; m < 64; m <<= 1) {
        s  += __shfl_xor(s, m);
        sq += __shfl_xor(sq, m);
    }
    const float mu  = s * (1.0f / Dc);
    const float var = fmaf(-mu, mu, sq * (1.0f / Dc));
    const float inv = rsqrtf(var + 1e-5f);

    float gm[8], bb[8];
    *(float4*)(gm + 0) = *(const float4*)(gamma + d0);
    *(float4*)(gm + 4) = *(const float4*)(gamma + d0 + 4);
    *(float4*)(bb + 0) = *(const float4*)(beta + d0);
    *(float4*)(bb + 4) = *(const float4*)(beta + d0 + 4);

    fvec4 y0, y1;
    y0.x = fmaf((x[0] - mu) * inv, gm[0], bb[0]);
    y0.y = fmaf((x[1] - mu) * inv, gm[1], bb[1]);
    y0.z = fmaf((x[2] - mu) * inv, gm[2], bb[2]);
    y0.w = fmaf((x[3] - mu) * inv, gm[3], bb[3]);
    y1.x = fmaf((x[4] - mu) * inv, gm[4], bb[4]);
    y1.y = fmaf((x[5] - mu) * inv, gm[5], bb[5]);
    y1.z = fmaf((x[6] - mu) * inv, gm[6], bb[6]);
    y1.w = fmaf((x[7] - mu) * inv, gm[7], bb[7]);

    float* op = out + (size_t)idx * Dc + d0;
    __builtin_nontemporal_store(y0, (fvec4*)(op + 0));
    __builtin_nontemporal_store(y1, (fvec4*)(op + 4));
}

extern "C" void kernel_launch(void* const* d_in, const int* in_sizes, int n_in,
                              void* d_out, int out_size, void* d_ws, size_t ws_size,
                              hipStream_t stream) {
    const int*   ids         = (const int*)d_in[0];
    const float* token_table = (const float*)d_in[1];
    const float* pos_table   = (const float*)d_in[2];
    const float* row_table   = (const float*)d_in[3];
    const float* col_table   = (const float*)d_in[4];
    const float* w_spatial   = (const float*)d_in[5];
    const float* ln_gamma    = (const float*)d_in[6];
    const float* ln_beta     = (const float*)d_in[7];
    float* out = (float*)d_out;

    char* ws = (char*)d_ws;
    int*   packed = (int*)ws;                         // 16*4096*4   = 256 KiB
    float* frow   = (float*)(ws + (256 << 10));       // 30*512*4    = 60 KiB
    float* fcol   = (float*)(ws + (256 << 10) + (64 << 10));

    hipLaunchKernelGGL(scan_pre_kernel, dim3(76), dim3(1024), 0, stream,
                       ids, packed, row_table, col_table, w_spatial, frow, fcol);
    hipLaunchKernelGGL(fuse_ln_kernel, dim3(Bc * Tc / 4), dim3(256), 0, stream,
                       ids, packed, token_table, pos_table, frow, fcol,
                       ln_gamma, ln_beta, out);
}

// Round 3
// 196.937 us; speedup vs baseline: 1.1242x; 1.0293x over previous
//
#include <hip/hip_runtime.h>
#include <hip/hip_bf16.h>

constexpr int PAD_T = 10, BOS_T = 11, EOS_T = 12, ROW_T = 13, SEP_T = 14;
constexpr int Bc = 16, Tc = 4096, Dc = 512;
constexpr int MAXH = 30, MAXW = 30;

typedef float fvec4 __attribute__((ext_vector_type(4)));

// Composable transition summary of a token chunk.
struct Summ { int r, c0, c1, g0, g1, rk, ck; };

__device__ inline void tok_update(int tok, Summ& s) {
    if (tok == BOS_T)      { s.g0 = 1; s.g1 = 1; s.r = 0; s.c0 = 0; s.c1 = 0; s.rk = 0; s.ck = 0; }
    else if (tok == SEP_T) { s.r = 0; s.c0 = 0; s.c1 = 0; s.rk = 0; s.ck = 0; }
    else if (tok == ROW_T) { s.r += 1; s.c0 = 0; s.c1 = 0; s.ck = 0; }
    else if (tok == EOS_T || tok == PAD_T) { s.g0 = 0; s.g1 = 0; }
    else { s.c0 += s.g0; s.c1 += s.g1; }   // digit 0..9
}

__device__ inline Summ compose(const Summ& a, const Summ& b) {
    Summ o;
    o.g0 = a.g0 ? b.g1 : b.g0;
    o.g1 = a.g1 ? b.g1 : b.g0;
    o.r  = b.rk ? a.r + b.r : b.r;
    o.rk = a.rk & b.rk;
    int cm0 = a.g0 ? b.c1 : b.c0;
    int cm1 = a.g1 ? b.c1 : b.c0;
    o.c0 = b.ck ? a.c0 + cm0 : cm0;
    o.c1 = b.ck ? a.c1 + cm1 : cm1;
    o.ck = a.ck & b.ck;
    return o;
}

__device__ inline void apply_state(const Summ& s, int& r, int& c, int& g) {
    int cm = g ? s.c1 : s.c0;
    r = s.rk ? r + s.r : s.r;
    c = s.ck ? c + cm : cm;
    g = g ? s.g1 : s.g0;
}

// ---------------------------------------------------------------------------
// Dispatch 1 (merged): blocks 0..15 = parallel automaton scan; blocks 16..75 =
// einsum collapse Frow = row_table @ W[:, :256]^T, Fcol = col_table @ W[:, 256:]^T.
// ---------------------------------------------------------------------------
__global__ __launch_bounds__(1024) void scan_pre_kernel(
        const int* __restrict__ ids, int* __restrict__ packed,
        const float* __restrict__ row_table, const float* __restrict__ col_table,
        const float* __restrict__ w,
        float* __restrict__ frow, float* __restrict__ fcol) {
    if (blockIdx.x < 16) {
        const int b = blockIdx.x;
        const int tid = threadIdx.x;          // 0..1023
        const int lane = tid & 63, wid = tid >> 6;

        const int4 tk4 = *(const int4*)(ids + b * Tc + tid * 4);
        int tks[4] = {tk4.x, tk4.y, tk4.z, tk4.w};

        Summ s{0, 0, 0, 0, 1, 1, 1};
#pragma unroll
        for (int j = 0; j < 4; ++j) tok_update(tks[j], s);

        Summ inc = s;
#pragma unroll
        for (int d = 1; d < 64; d <<= 1) {
            Summ o;
            o.r  = __shfl_up(inc.r, d);
            o.c0 = __shfl_up(inc.c0, d);
            o.c1 = __shfl_up(inc.c1, d);
            o.g0 = __shfl_up(inc.g0, d);
            o.g1 = __shfl_up(inc.g1, d);
            o.rk = __shfl_up(inc.rk, d);
            o.ck = __shfl_up(inc.ck, d);
            if (lane >= d) inc = compose(o, inc);
        }

        __shared__ int lsum[16][7];
        if (lane == 63) {
            lsum[wid][0] = inc.r;  lsum[wid][1] = inc.c0; lsum[wid][2] = inc.c1;
            lsum[wid][3] = inc.g0; lsum[wid][4] = inc.g1;
            lsum[wid][5] = inc.rk; lsum[wid][6] = inc.ck;
        }
        __syncthreads();

        int wr = 0, wc = 0, wg = 0;
        for (int w2 = 0; w2 < wid; ++w2) {
            Summ t;
            t.r  = lsum[w2][0]; t.c0 = lsum[w2][1]; t.c1 = lsum[w2][2];
            t.g0 = lsum[w2][3]; t.g1 = lsum[w2][4];
            t.rk = lsum[w2][5]; t.ck = lsum[w2][6];
            apply_state(t, wr, wc, wg);
        }

        Summ ex;
        ex.r  = __shfl_up(inc.r, 1);  ex.c0 = __shfl_up(inc.c0, 1);
        ex.c1 = __shfl_up(inc.c1, 1); ex.g0 = __shfl_up(inc.g0, 1);
        ex.g1 = __shfl_up(inc.g1, 1); ex.rk = __shfl_up(inc.rk, 1);
        ex.ck = __shfl_up(inc.ck, 1);
        if (lane == 0) { ex = Summ{0, 0, 0, 0, 1, 1, 1}; }
        int row = wr, col = wc, grid = wg;
        apply_state(ex, row, col, grid);

        int o4[4];
#pragma unroll
        for (int j = 0; j < 4; ++j) {
            int tok = tks[j];
            int gc = grid & (tok <= 9);
            int er = gc ? min(row, MAXH - 1) : 0;
            int ec = gc ? min(col, MAXW - 1) : 0;
            o4[j] = (er << 5) | ec;
            if (tok == BOS_T)      { grid = 1; row = 0; col = 0; }
            else if (tok == SEP_T) { row = 0; col = 0; }
            else if (tok == ROW_T) { row += 1; col = 0; }
            else if (tok == EOS_T || tok == PAD_T) { grid = 0; }
            else { col += gc; }
        }
        *(int4*)(packed + b * Tc + tid * 4) = make_int4(o4[0], o4[1], o4[2], o4[3]);
    } else {
        const int blk = blockIdx.x - 16;
        const int which = blk / 30;            // 0 -> Frow, 1 -> Fcol
        const int rr = blk % 30;
        const float* src = which ? (col_table + rr * 256) : (row_table + rr * 256);
        float* dst = which ? (fcol + rr * Dc) : (frow + rr * Dc);
        const int doff = which ? 256 : 0;

        __shared__ __align__(16) float sv[256];
        if (threadIdx.x < 256) sv[threadIdx.x] = src[threadIdx.x];
        __syncthreads();

        if (threadIdx.x < 512) {
            const int e = threadIdx.x;
            const float4* a4 = (const float4*)sv;
            const float4* w4 = (const float4*)(w + (size_t)e * Dc + doff);
            float acc = 0.f;
#pragma unroll 8
            for (int k = 0; k < 64; ++k) {
                float4 a = a4[k];
                float4 wb = w4[k];
                acc += a.x * wb.x + a.y * wb.y + a.z * wb.z + a.w * wb.w;
            }
            dst[e] = acc;
        }
    }
}

// ---------------------------------------------------------------------------
// Dispatch 2: fused embed-add + LayerNorm. TWO tokens per wave (same t,
// b and b+8): pos/gamma/beta registers shared, two independent reductions
// interleaved to halve exposed shuffle-chain latency. t-major for pos L2 reuse.
// ---------------------------------------------------------------------------
__global__ __launch_bounds__(256) void fuse_ln_kernel(
        const int* __restrict__ ids, const int* __restrict__ packed,
        const float* __restrict__ token_table, const float* __restrict__ pos_table,
        const float* __restrict__ frow, const float* __restrict__ fcol,
        const float* __restrict__ gamma, const float* __restrict__ beta,
        float* __restrict__ out) {
    const int wave = threadIdx.x >> 6;
    const int lane = threadIdx.x & 63;
    const int g2 = blockIdx.x * 4 + wave;    // [0, 8*T): (t, b0) with b0 in [0,8)
    const int b0 = g2 & 7;
    const int t  = g2 >> 3;
    const int idx0 = b0 * Tc + t;
    const int idx1 = idx0 + 8 * Tc;
    const int d0 = lane * 8;

    const int tok0 = ids[idx0];
    const int tok1 = ids[idx1];
    const int pk0 = packed[idx0];
    const int pk1 = packed[idx1];

    float xp[8];
    *(float4*)(xp + 0) = *(const float4*)(pos_table + (size_t)t * Dc + d0);
    *(float4*)(xp + 4) = *(const float4*)(pos_table + (size_t)t * Dc + d0 + 4);

    float x0[8], x1[8];
    {
        float xt[8];
        *(float4*)(xt + 0) = *(const float4*)(token_table + (size_t)tok0 * Dc + d0);
        *(float4*)(xt + 4) = *(const float4*)(token_table + (size_t)tok0 * Dc + d0 + 4);
#pragma unroll
        for (int j = 0; j < 8; ++j) x0[j] = xt[j] + xp[j];
    }
    {
        float xt[8];
        *(float4*)(xt + 0) = *(const float4*)(token_table + (size_t)tok1 * Dc + d0);
        *(float4*)(xt + 4) = *(const float4*)(token_table + (size_t)tok1 * Dc + d0 + 4);
#pragma unroll
        for (int j = 0; j < 8; ++j) x1[j] = xt[j] + xp[j];
    }

    if (tok0 <= 9) {                         // wave-uniform
        const int rI = pk0 >> 5, cI = pk0 & 31;
        float xf[8], xc[8];
        *(float4*)(xf + 0) = *(const float4*)(frow + (size_t)rI * Dc + d0);
        *(float4*)(xf + 4) = *(const float4*)(frow + (size_t)rI * Dc + d0 + 4);
        *(float4*)(xc + 0) = *(const float4*)(fcol + (size_t)cI * Dc + d0);
        *(float4*)(xc + 4) = *(const float4*)(fcol + (size_t)cI * Dc + d0 + 4);
#pragma unroll
        for (int j = 0; j < 8; ++j) x0[j] += xf[j] + xc[j];
    }
    if (tok1 <= 9) {                         // wave-uniform
        const int rI = pk1 >> 5, cI = pk1 & 31;
        float xf[8], xc[8];
        *(float4*)(xf + 0) = *(const float4*)(frow + (size_t)rI * Dc + d0);
        *(float4*)(xf + 4) = *(const float4*)(frow + (size_t)rI * Dc + d0 + 4);
        *(float4*)(xc + 0) = *(const float4*)(fcol + (size_t)cI * Dc + d0);
        *(float4*)(xc + 4) = *(const float4*)(fcol + (size_t)cI * Dc + d0 + 4);
#pragma unroll
        for (int j = 0; j < 8; ++j) x1[j] += xf[j] + xc[j];
    }

    float s0 = 0.f, q0 = 0.f, s1 = 0.f, q1 = 0.f;
#pragma unroll
    for (int j = 0; j < 8; ++j) {
        s0 += x0[j]; q0 = fmaf(x0[j], x0[j], q0);
        s1 += x1[j]; q1 = fmaf(x1[j], x1[j], q1);
    }
    // two independent butterfly reductions, interleaved for ILP
#pragma unroll
    for (int m = 1; m < 64; m <<= 1) {
        s0 += __shfl_xor(s0, m);
        s1 += __shfl_xor(s1, m);
        q0 += __shfl_xor(q0, m);
        q1 += __shfl_xor(q1, m);
    }
    const float mu0  = s0 * (1.0f / Dc);
    const float mu1  = s1 * (1.0f / Dc);
    const float var0 = fmaf(-mu0, mu0, q0 * (1.0f / Dc));
    const float var1 = fmaf(-mu1, mu1, q1 * (1.0f / Dc));
    const float inv0 = rsqrtf(var0 + 1e-5f);
    const float inv1 = rsqrtf(var1 + 1e-5f);

    float gm[8], bb[8];
    *(float4*)(gm + 0) = *(const float4*)(gamma + d0);
    *(float4*)(gm + 4) = *(const float4*)(gamma + d0 + 4);
    *(float4*)(bb + 0) = *(const float4*)(beta + d0);
    *(float4*)(bb + 4) = *(const float4*)(beta + d0 + 4);

    fvec4 y0a, y0b, y1a, y1b;
    y0a.x = fmaf((x0[0] - mu0) * inv0, gm[0], bb[0]);
    y0a.y = fmaf((x0[1] - mu0) * inv0, gm[1], bb[1]);
    y0a.z = fmaf((x0[2] - mu0) * inv0, gm[2], bb[2]);
    y0a.w = fmaf((x0[3] - mu0) * inv0, gm[3], bb[3]);
    y0b.x = fmaf((x0[4] - mu0) * inv0, gm[4], bb[4]);
    y0b.y = fmaf((x0[5] - mu0) * inv0, gm[5], bb[5]);
    y0b.z = fmaf((x0[6] - mu0) * inv0, gm[6], bb[6]);
    y0b.w = fmaf((x0[7] - mu0) * inv0, gm[7], bb[7]);
    y1a.x = fmaf((x1[0] - mu1) * inv1, gm[0], bb[0]);
    y1a.y = fmaf((x1[1] - mu1) * inv1, gm[1], bb[1]);
    y1a.z = fmaf((x1[2] - mu1) * inv1, gm[2], bb[2]);
    y1a.w = fmaf((x1[3] - mu1) * inv1, gm[3], bb[3]);
    y1b.x = fmaf((x1[4] - mu1) * inv1, gm[4], bb[4]);
    y1b.y = fmaf((x1[5] - mu1) * inv1, gm[5], bb[5]);
    y1b.z = fmaf((x1[6] - mu1) * inv1, gm[6], bb[6]);
    y1b.w = fmaf((x1[7] - mu1) * inv1, gm[7], bb[7]);

    float* op0 = out + (size_t)idx0 * Dc + d0;
    float* op1 = out + (size_t)idx1 * Dc + d0;
    __builtin_nontemporal_store(y0a, (fvec4*)(op0 + 0));
    __builtin_nontemporal_store(y0b, (fvec4*)(op0 + 4));
    __builtin_nontemporal_store(y1a, (fvec4*)(op1 + 0));
    __builtin_nontemporal_store(y1b, (fvec4*)(op1 + 4));
}

extern "C" void kernel_launch(void* const* d_in, const int* in_sizes, int n_in,
                              void* d_out, int out_size, void* d_ws, size_t ws_size,
                              hipStream_t stream) {
    const int*   ids         = (const int*)d_in[0];
    const float* token_table = (const float*)d_in[1];
    const float* pos_table   = (const float*)d_in[2];
    const float* row_table   = (const float*)d_in[3];
    const float* col_table   = (const float*)d_in[4];
    const float* w_spatial   = (const float*)d_in[5];
    const float* ln_gamma    = (const float*)d_in[6];
    const float* ln_beta     = (const float*)d_in[7];
    float* out = (float*)d_out;

    char* ws = (char*)d_ws;
    int*   packed = (int*)ws;                         // 16*4096*4   = 256 KiB
    float* frow   = (float*)(ws + (256 << 10));       // 30*512*4    = 60 KiB
    float* fcol   = (float*)(ws + (256 << 10) + (64 << 10));

    hipLaunchKernelGGL(scan_pre_kernel, dim3(76), dim3(1024), 0, stream,
                       ids, packed, row_table, col_table, w_spatial, frow, fcol);
    hipLaunchKernelGGL(fuse_ln_kernel, dim3(Bc * Tc / 8), dim3(256), 0, stream,
                       ids, packed, token_table, pos_table, frow, fcol,
                       ln_gamma, ln_beta, out);
}